// Round 1
// baseline (57.182 us; speedup 1.0000x reference)
//
#include <hip/hip_runtime.h>

// LocalizationAttacks: per-segment (1600 samples) attack decision applied
// elementwise to B x T audio. Reference outputs (concatenated flat):
//   attacked        = c==0 ? watermarked : (c==1 ? original : 0)
//   ground_truth    = c==0 ? 1 : 0
//   update_original = c==2 ? 0 : original
// where c = 0 (not attacked), 1 (attacked & revert), 2 (attacked & zeroed).

#define SEGLEN 1600
#define NSEG   300     // S = T / SEGLEN for the reference shapes

// Kernel 1: build per-(b,s) code array in workspace.
// code[b*S+s] = 0 default; = 1 if s in seg_starts[b] and revert_flags[b][s]
//             = 2 if s in seg_starts[b] and !revert_flags[b][s]
__global__ void build_code_kernel(const int* __restrict__ seg_starts,
                                  const int* __restrict__ revert_flags,
                                  int* __restrict__ code,
                                  int S, int S_mod) {
    const int b = blockIdx.x;
    for (int s = threadIdx.x; s < S; s += blockDim.x)
        code[b * S + s] = 0;
    __syncthreads();
    for (int i = threadIdx.x; i < S_mod; i += blockDim.x) {
        const int s = seg_starts[b * S_mod + i];
        // duplicates write the same value -> benign race
        code[b * S + s] = revert_flags[b * S + s] ? 1 : 2;
    }
}

// Kernel 2: elementwise float4 pass. One thread = 4 samples (SEGLEN % 4 == 0,
// so a float4 never straddles a segment boundary).
__global__ void attack_kernel(const float4* __restrict__ orig,
                              const float4* __restrict__ wm,
                              const int*    __restrict__ code,
                              float4*       __restrict__ out,
                              int N4,          // T/4 float4s per batch row
                              int S,
                              long long BT4)   // B * N4 (output plane stride in float4)
{
    const int b  = blockIdx.y;
    const int i4 = blockIdx.x * blockDim.x + threadIdx.x;
    if (i4 >= N4) return;

    const int t = i4 * 4;
    const int s = t / SEGLEN;                 // magic-mul divide by constant
    const int c = code[b * S + s];            // tiny array, L1/L2 resident

    const long long base = (long long)b * N4 + i4;
    const float4 o = orig[base];
    const float4 w = wm[base];
    const float4 z    = make_float4(0.f, 0.f, 0.f, 0.f);
    const float4 ones = make_float4(1.f, 1.f, 1.f, 1.f);

    const float4 att = (c == 0) ? w : ((c == 1) ? o : z);
    const float4 gt  = (c == 0) ? ones : z;
    const float4 up  = (c == 2) ? z : o;

    out[base]           = att;   // attacked
    out[base + BT4]     = gt;    // ground_truth
    out[base + 2 * BT4] = up;    // update_original
}

extern "C" void kernel_launch(void* const* d_in, const int* in_sizes, int n_in,
                              void* d_out, int out_size, void* d_ws, size_t ws_size,
                              hipStream_t stream) {
    const float* orig       = (const float*)d_in[0];
    const float* wm         = (const float*)d_in[1];
    const int*   seg_starts = (const int*)d_in[2];
    const int*   rflags     = (const int*)d_in[3];
    float*       out        = (float*)d_out;

    // Derive shapes from input sizes (reference: B=32, S=300, S_mod=60, T=480000)
    const int S     = NSEG;
    const int B     = in_sizes[3] / S;          // revert_flags is [B, S]
    const int S_mod = in_sizes[2] / B;          // seg_starts is [B, S_mod]
    const int T     = in_sizes[0] / B;          // original is [B, 1, T]

    int* code = (int*)d_ws;                     // B*S ints = 38.4 KB

    build_code_kernel<<<B, 128, 0, stream>>>(seg_starts, rflags, code, S, S_mod);

    const int N4 = T / 4;                       // 120000
    const long long BT4 = (long long)B * N4;    // 3,840,000
    dim3 grid((N4 + 255) / 256, B);
    attack_kernel<<<grid, 256, 0, stream>>>(
        (const float4*)orig, (const float4*)wm, code, (float4*)out, N4, S, BT4);
}